// Round 1
// 455.434 us; speedup vs baseline: 1.3756x; 1.3756x over previous
//
#include <hip/hip_runtime.h>
#include <stdint.h>

#define BROWS 16384
#define DIMN 1024
#define HIDN 64

typedef __attribute__((ext_vector_type(8))) short bf16x8;
typedef __attribute__((ext_vector_type(4))) float f32x4;

__device__ __forceinline__ unsigned short f2bf(float f) {
    union { float f; unsigned int u; } v; v.f = f;
    unsigned int u = v.u;
    u += 0x7fffu + ((u >> 16) & 1u);   // round-to-nearest-even
    return (unsigned short)(u >> 16);
}

__device__ __forceinline__ bf16x8 pack8(float4 a, float4 b) {
    bf16x8 r;
    r[0] = (short)f2bf(a.x); r[1] = (short)f2bf(a.y);
    r[2] = (short)f2bf(a.z); r[3] = (short)f2bf(a.w);
    r[4] = (short)f2bf(b.x); r[5] = (short)f2bf(b.y);
    r[6] = (short)f2bf(b.z); r[7] = (short)f2bf(b.w);
    return r;
}

__device__ __forceinline__ float geluf(float x) {
    return 0.5f * x * (1.0f + erff(x * 0.70710678118654752f));
}
__device__ __forceinline__ float dgeluf(float x) {
    float c = 0.5f * (1.0f + erff(x * 0.70710678118654752f));
    return c + x * 0.3989422804014327f * expf(-0.5f * x * x);
}

// ---------------- prep kernels ----------------

__global__ void w2sum_kernel(const float* __restrict__ W2, float* __restrict__ w2sum) {
    __shared__ float part[4][64];
    int k = threadIdx.x & 63, c = threadIdx.x >> 6;
    float s = 0.f;
    const float* row = W2 + (size_t)k * DIMN + c * 256;
    for (int j = 0; j < 256; ++j) s += row[j];
    part[c][k] = s;
    __syncthreads();
    if (c == 0) w2sum[k] = part[0][k] + part[1][k] + part[2][k] + part[3][k];
}

// W1bf  [2048][64]  : W1 rows, bf16 (B^T for D = u @ W1q^T)
// W1Tbf [64][2048]  : W1^T, bf16 (B^T for z = X @ W1, and A for mnkern)
// W2Tbf [1024][64]  : W2^T, bf16 (B^T for E = g @ W2)
// W1qdT [64][1024]  : (diag(dt/mass) @ W1q)^T, bf16
__global__ void prep_kernel(const float* __restrict__ W1, const float* __restrict__ W2,
                            const float* __restrict__ mass, const float* __restrict__ dtp,
                            unsigned short* __restrict__ W1bf,
                            unsigned short* __restrict__ W1Tbf,
                            unsigned short* __restrict__ W2Tbf,
                            unsigned short* __restrict__ W1qdT,
                            float* __restrict__ dtm) {
    int gid = blockIdx.x * blockDim.x + threadIdx.x;
    int nt = gridDim.x * blockDim.x;
    float dt = 1.0f / (1.0f + expf(-dtp[0]));
    for (int i = gid; i < 2048 * 64; i += nt) {
        unsigned short b = f2bf(W1[i]);
        W1bf[i] = b;
        int k = i >> 6, n = i & 63;
        W1Tbf[n * 2048 + k] = b;
    }
    for (int i = gid; i < 64 * 1024; i += nt) {
        int k = i >> 10, n = i & 1023;
        W2Tbf[n * 64 + k] = f2bf(W2[i]);
    }
    for (int i = gid; i < 64 * 1024; i += nt) {
        int n = i >> 10, k = i & 1023;
        W1qdT[i] = f2bf((dt / mass[k]) * W1[k * 64 + n]);
    }
    for (int i = gid; i < DIMN; i += nt) dtm[i] = dt / mass[i];
}

// ---------------- mnkern: MN = W1q^T (diag(dtm) W1q + W1p), Nm = W1q^T W1p ----------------
// 64x64 fp32 outputs via bf16 MFMA, K=1024. 16 waves.

__global__ __launch_bounds__(256)
void mnkern(const unsigned short* __restrict__ W1T, const unsigned short* __restrict__ W1qdT,
            float* __restrict__ MN, float* __restrict__ Nm) {
    const int wv = threadIdx.x >> 6, lane = threadIdx.x & 63;
    const int l16 = lane & 15, quad = lane >> 4, kq = quad * 8;
    const int gw = blockIdx.x * 4 + wv;       // 0..15
    const int mt = gw >> 2, nt = gw & 3;
    f32x4 accMd = {0,0,0,0}, accN = {0,0,0,0};
    #pragma unroll 4
    for (int it = 0; it < 32; ++it) {
        int k = it * 32 + kq;
        bf16x8 af = *(const bf16x8*)(W1T + (size_t)(mt * 16 + l16) * 2048 + k);
        bf16x8 bd = *(const bf16x8*)(W1qdT + (size_t)(nt * 16 + l16) * 1024 + k);
        bf16x8 bp = *(const bf16x8*)(W1T + (size_t)(nt * 16 + l16) * 2048 + 1024 + k);
        accMd = __builtin_amdgcn_mfma_f32_16x16x32_bf16(af, bd, accMd, 0, 0, 0);
        accN  = __builtin_amdgcn_mfma_f32_16x16x32_bf16(af, bp, accN, 0, 0, 0);
    }
    #pragma unroll
    for (int rg = 0; rg < 4; ++rg) {
        int row = mt * 16 + quad * 4 + rg;
        int col = nt * 16 + l16;
        MN[row * 64 + col] = accMd[rg] + accN[rg];
        Nm[row * 64 + col] = accN[rg];
    }
}

// ---------------- zdual: z1 = [q,p]@W1 + b1, zdp = (dtm .* p)@W1q ----------------
// One block (4 waves) per 16-row tile; each wave a 256-col K-slice of q AND p.
// LDS reduce of the 4 partials. 1024 blocks, 4096 waves.

__global__ __launch_bounds__(256, 4)
void zdual(const float* __restrict__ q, const float* __restrict__ p,
           const unsigned short* __restrict__ W1T, const unsigned short* __restrict__ W1qdT,
           const float* __restrict__ b1,
           float* __restrict__ z1g, float* __restrict__ zdpg) {
    __shared__ float part[4 * 64 * 34];       // [wave][lane][16 z | 16 d], stride 34 (2-way max)
    const int wv = threadIdx.x >> 6, lane = threadIdx.x & 63;
    const int l16 = lane & 15, quad = lane >> 4, kq = quad * 8;
    const int tile = blockIdx.x;              // 16-row tile, 0..1023
    const size_t arow = (size_t)tile * 16 + l16;
    const float* rq = q + arow * DIMN;
    const float* rp = p + arow * DIMN;
    const int k0 = wv * 256;

    f32x4 accz[4] = {{0,0,0,0},{0,0,0,0},{0,0,0,0},{0,0,0,0}};
    f32x4 accd[4] = {{0,0,0,0},{0,0,0,0},{0,0,0,0},{0,0,0,0}};

    // q slice: z += q @ W1q[k-slice]
    #pragma unroll 4
    for (int it = 0; it < 8; ++it) {
        int k = k0 + it * 32 + kq;
        float4 a0 = *(const float4*)(rq + k);
        float4 a1 = *(const float4*)(rq + k + 4);
        bf16x8 af = pack8(a0, a1);
        #pragma unroll
        for (int c = 0; c < 4; ++c) {
            bf16x8 bf = *(const bf16x8*)(W1T + (size_t)(c * 16 + l16) * 2048 + k);
            accz[c] = __builtin_amdgcn_mfma_f32_16x16x32_bf16(af, bf, accz[c], 0, 0, 0);
        }
    }
    // p slice: z += p @ W1p[k-slice];  zdp += p @ (diag(dtm) W1q)[k-slice]
    #pragma unroll 2
    for (int it = 0; it < 8; ++it) {
        int k = k0 + it * 32 + kq;
        float4 a0 = *(const float4*)(rp + k);
        float4 a1 = *(const float4*)(rp + k + 4);
        bf16x8 af = pack8(a0, a1);
        #pragma unroll
        for (int c = 0; c < 4; ++c) {
            bf16x8 bfp = *(const bf16x8*)(W1T + (size_t)(c * 16 + l16) * 2048 + 1024 + k);
            accz[c] = __builtin_amdgcn_mfma_f32_16x16x32_bf16(af, bfp, accz[c], 0, 0, 0);
            bf16x8 bfd = *(const bf16x8*)(W1qdT + (size_t)(c * 16 + l16) * 1024 + k);
            accd[c] = __builtin_amdgcn_mfma_f32_16x16x32_bf16(af, bfd, accd[c], 0, 0, 0);
        }
    }

    float* myp = part + (size_t)(wv * 64 + lane) * 34;
    #pragma unroll
    for (int c = 0; c < 4; ++c) {
        #pragma unroll
        for (int rg = 0; rg < 4; ++rg) {
            myp[c * 4 + rg] = accz[c][rg];
            myp[16 + c * 4 + rg] = accd[c][rg];
        }
    }
    __syncthreads();
    for (int e = threadIdx.x; e < 1024; e += 256) {
        int row = e >> 6, col = e & 63;
        int ln = ((row >> 2) << 4) | (col & 15);
        int j = ((col >> 4) << 2) | (row & 3);
        float sz = b1[col], sd = 0.f;
        #pragma unroll
        for (int w = 0; w < 4; ++w) {
            const float* pp = part + (size_t)(w * 64 + ln) * 34;
            sz += pp[j];
            sd += pp[16 + j];
        }
        size_t o = ((size_t)tile * 16 + row) * 64 + col;
        z1g[o] = sz;
        zdpg[o] = sd;
    }
}

// ---------------- chain: per-row 64-dim leapfrog recurrences (fp32) ----------------
// u1 = dgelu(z1)*w2sum; z2 = z1 + zdp - hdt*u1@MN; u2 = dgelu(z2)*w2sum;
// z3 = z2 - hdt*u2@Nm; outputs u1, u1+u2, gelu(z1)-gelu(z3) as bf16.
// One wave per 4 rows; lane = column. 4096 waves.

__global__ __launch_bounds__(256, 4)
void chain(const float* __restrict__ z1g, const float* __restrict__ zdpg,
           const float* __restrict__ MN, const float* __restrict__ Nm,
           const float* __restrict__ w2sum, const float* __restrict__ dtp,
           unsigned short* __restrict__ u1b, unsigned short* __restrict__ usb,
           unsigned short* __restrict__ g13) {
    __shared__ float ubuf[4 * 256];           // wave-private broadcast buffers
    const int wv = threadIdx.x >> 6, lane = threadIdx.x & 63;
    float* ub = ubuf + wv * 256;
    const int r0 = (blockIdx.x * 4 + wv) * 4;
    const float ws = w2sum[lane];
    const float hdt = 0.5f / (1.0f + expf(-dtp[0]));

    float z1v[4], zdv[4], u1[4], h1[4];
    #pragma unroll
    for (int r = 0; r < 4; ++r) {
        z1v[r] = z1g[(size_t)(r0 + r) * 64 + lane];
        zdv[r] = zdpg[(size_t)(r0 + r) * 64 + lane];
        u1[r] = dgeluf(z1v[r]) * ws;
        h1[r] = geluf(z1v[r]);
        ub[r * 64 + lane] = u1[r];
    }
    float acc[4] = {0.f, 0.f, 0.f, 0.f};
    #pragma unroll 8
    for (int k = 0; k < 64; ++k) {
        float m = MN[k * 64 + lane];
        acc[0] += ub[k] * m;
        acc[1] += ub[64 + k] * m;
        acc[2] += ub[128 + k] * m;
        acc[3] += ub[192 + k] * m;
    }
    float z2[4], u2[4];
    #pragma unroll
    for (int r = 0; r < 4; ++r) {
        z2[r] = z1v[r] + zdv[r] - hdt * acc[r];
        u2[r] = dgeluf(z2[r]) * ws;
        ub[r * 64 + lane] = u2[r];
    }
    float acc2[4] = {0.f, 0.f, 0.f, 0.f};
    #pragma unroll 8
    for (int k = 0; k < 64; ++k) {
        float m = Nm[k * 64 + lane];
        acc2[0] += ub[k] * m;
        acc2[1] += ub[64 + k] * m;
        acc2[2] += ub[128 + k] * m;
        acc2[3] += ub[192 + k] * m;
    }
    #pragma unroll
    for (int r = 0; r < 4; ++r) {
        float z3 = z2[r] - hdt * acc2[r];
        size_t o = (size_t)(r0 + r) * 64 + lane;
        u1b[o] = f2bf(u1[r]);
        usb[o] = f2bf(u1[r] + u2[r]);
        g13[o] = f2bf(h1[r] - geluf(z3));
    }
}

// ---------------- widefused: all three 64-MB outputs in one pass ----------------
// Per wave: one 16x16 tile of Dq = u1@W1q^T, Ds = (u1+u2)@W1q^T, E = g13@W2 (6 MFMAs),
// then outq = q + dtm*(p - hdt*Dq); outp = p - hdt*Ds; oute = |E|. 65536 waves.

__global__ __launch_bounds__(256, 4)
void widefused(const unsigned short* __restrict__ u1b, const unsigned short* __restrict__ usb,
               const unsigned short* __restrict__ g13,
               const unsigned short* __restrict__ W1bf, const unsigned short* __restrict__ W2T,
               const float* __restrict__ q, const float* __restrict__ p,
               const float* __restrict__ dtm, const float* __restrict__ dtp,
               float* __restrict__ outq, float* __restrict__ outp, float* __restrict__ oute) {
    const int wv = threadIdx.x >> 6, lane = threadIdx.x & 63;
    const int l16 = lane & 15, quad = lane >> 4, kq = quad * 8;
    const int gw = blockIdx.x * 4 + wv;       // 0..65535
    const int mt = gw >> 6, nt = gw & 63;
    const size_t arow = (size_t)mt * 16 + l16;
    const int n0 = nt * 16;

    bf16x8 au0 = *(const bf16x8*)(u1b + arow * 64 + kq);
    bf16x8 au1 = *(const bf16x8*)(u1b + arow * 64 + 32 + kq);
    bf16x8 as0 = *(const bf16x8*)(usb + arow * 64 + kq);
    bf16x8 as1 = *(const bf16x8*)(usb + arow * 64 + 32 + kq);
    bf16x8 ag0 = *(const bf16x8*)(g13 + arow * 64 + kq);
    bf16x8 ag1 = *(const bf16x8*)(g13 + arow * 64 + 32 + kq);
    bf16x8 bw0 = *(const bf16x8*)(W1bf + (size_t)(n0 + l16) * 64 + kq);
    bf16x8 bw1 = *(const bf16x8*)(W1bf + (size_t)(n0 + l16) * 64 + 32 + kq);
    bf16x8 b20 = *(const bf16x8*)(W2T + (size_t)(n0 + l16) * 64 + kq);
    bf16x8 b21 = *(const bf16x8*)(W2T + (size_t)(n0 + l16) * 64 + 32 + kq);

    f32x4 accq = {0,0,0,0}, accs = {0,0,0,0}, acce = {0,0,0,0};
    accq = __builtin_amdgcn_mfma_f32_16x16x32_bf16(au0, bw0, accq, 0, 0, 0);
    accq = __builtin_amdgcn_mfma_f32_16x16x32_bf16(au1, bw1, accq, 0, 0, 0);
    accs = __builtin_amdgcn_mfma_f32_16x16x32_bf16(as0, bw0, accs, 0, 0, 0);
    accs = __builtin_amdgcn_mfma_f32_16x16x32_bf16(as1, bw1, accs, 0, 0, 0);
    acce = __builtin_amdgcn_mfma_f32_16x16x32_bf16(ag0, b20, acce, 0, 0, 0);
    acce = __builtin_amdgcn_mfma_f32_16x16x32_bf16(ag1, b21, acce, 0, 0, 0);

    const int i = n0 + l16;
    const float hdt = 0.5f / (1.0f + expf(-dtp[0]));
    const float dm = dtm[i];
    #pragma unroll
    for (int rg = 0; rg < 4; ++rg) {
        size_t idx = (size_t)(mt * 16 + quad * 4 + rg) * DIMN + i;
        float qv = q[idx], pv = p[idx];
        float ph = pv - hdt * accq[rg];
        outq[idx] = qv + dm * ph;
        outp[idx] = pv - hdt * accs[rg];
        oute[idx] = fabsf(acce[rg]);
    }
}

// ---------------- launch ----------------

extern "C" void kernel_launch(void* const* d_in, const int* in_sizes, int n_in,
                              void* d_out, int out_size, void* d_ws, size_t ws_size,
                              hipStream_t stream) {
    const float* q    = (const float*)d_in[0];
    const float* p    = (const float*)d_in[1];
    const float* W1   = (const float*)d_in[2];
    const float* b1   = (const float*)d_in[3];
    const float* W2   = (const float*)d_in[4];
    /* b2 = d_in[5] cancels everywhere */
    const float* mass = (const float*)d_in[6];
    const float* dtp  = (const float*)d_in[7];

    float* out  = (float*)d_out;
    float* outq = out;
    float* outp = out + (size_t)BROWS * DIMN;
    float* oute = out + (size_t)2 * BROWS * DIMN;

    char* ws = (char*)d_ws;
    unsigned short* W1bf  = (unsigned short*)(ws);              // 256 KB [2048][64]
    unsigned short* W1Tbf = (unsigned short*)(ws + 262144);     // 256 KB [64][2048]
    unsigned short* W2Tbf = (unsigned short*)(ws + 524288);     // 128 KB [1024][64]
    float* w2sum          = (float*)(ws + 655360);              // 256 B
    float* dtm            = (float*)(ws + 655616);              // 4 KB
    unsigned short* W1qdT = (unsigned short*)(ws + 659712);     // 128 KB [64][1024]
    float* MN             = (float*)(ws + 790784);              // 16 KB [64][64]
    float* Nm             = (float*)(ws + 807168);              // 16 KB [64][64]
    float* z1             = (float*)(ws + 1048576);             // 4 MB [16384][64]
    float* zdp            = (float*)(ws + 5242880);             // 4 MB [16384][64]
    unsigned short* u1b   = (unsigned short*)(ws + 9437184);    // 2 MB
    unsigned short* usb   = (unsigned short*)(ws + 11534336);   // 2 MB
    unsigned short* g13   = (unsigned short*)(ws + 13631488);   // 2 MB

    hipLaunchKernelGGL(w2sum_kernel, dim3(1), dim3(256), 0, stream, W2, w2sum);
    hipLaunchKernelGGL(prep_kernel, dim3(256), dim3(256), 0, stream,
                       W1, W2, mass, dtp, W1bf, W1Tbf, W2Tbf, W1qdT, dtm);
    hipLaunchKernelGGL(mnkern, dim3(4), dim3(256), 0, stream, W1Tbf, W1qdT, MN, Nm);
    hipLaunchKernelGGL(zdual, dim3(1024), dim3(256), 0, stream,
                       q, p, W1Tbf, W1qdT, b1, z1, zdp);
    hipLaunchKernelGGL(chain, dim3(1024), dim3(256), 0, stream,
                       z1, zdp, MN, Nm, w2sum, dtp, u1b, usb, g13);
    hipLaunchKernelGGL(widefused, dim3(16384), dim3(256), 0, stream,
                       u1b, usb, g13, W1bf, W2Tbf, q, p, dtm, dtp, outq, outp, oute);
}

// Round 2
// 428.499 us; speedup vs baseline: 1.4620x; 1.0629x over previous
//
#include <hip/hip_runtime.h>
#include <stdint.h>

#define BROWS 16384
#define DIMN 1024
#define HIDN 64

typedef __attribute__((ext_vector_type(8))) short bf16x8;
typedef __attribute__((ext_vector_type(4))) float f32x4;

__device__ __forceinline__ unsigned short f2bf(float f) {
    union { float f; unsigned int u; } v; v.f = f;
    unsigned int u = v.u;
    u += 0x7fffu + ((u >> 16) & 1u);   // round-to-nearest-even
    return (unsigned short)(u >> 16);
}

__device__ __forceinline__ bf16x8 pack8(float4 a, float4 b) {
    bf16x8 r;
    r[0] = (short)f2bf(a.x); r[1] = (short)f2bf(a.y);
    r[2] = (short)f2bf(a.z); r[3] = (short)f2bf(a.w);
    r[4] = (short)f2bf(b.x); r[5] = (short)f2bf(b.y);
    r[6] = (short)f2bf(b.z); r[7] = (short)f2bf(b.w);
    return r;
}

__device__ __forceinline__ float geluf(float x) {
    return 0.5f * x * (1.0f + erff(x * 0.70710678118654752f));
}
__device__ __forceinline__ float dgeluf(float x) {
    float c = 0.5f * (1.0f + erff(x * 0.70710678118654752f));
    return c + x * 0.3989422804014327f * expf(-0.5f * x * x);
}

// ---------------- prep: w2sum (block 0) + bf16 weight packs ----------------
// W1bf  [2048][64]  : W1 rows, bf16 (B^T for D = u @ W1q^T)
// W1Tbf [64][2048]  : W1^T, bf16 (B^T for z = X @ W1, A for mnkern)
// W2Tbf [1024][64]  : W2^T, bf16 (B^T for E = g @ W2)
// W1qdT [64][1024]  : (diag(dt/mass) @ W1q)^T, bf16

__global__ void prep_kernel(const float* __restrict__ W1, const float* __restrict__ W2,
                            const float* __restrict__ mass, const float* __restrict__ dtp,
                            unsigned short* __restrict__ W1bf,
                            unsigned short* __restrict__ W1Tbf,
                            unsigned short* __restrict__ W2Tbf,
                            unsigned short* __restrict__ W1qdT,
                            float* __restrict__ dtm, float* __restrict__ w2sum) {
    if (blockIdx.x == 0) {   // w2sum[k] = sum_j W2[k][j]
        __shared__ float partw[4][64];
        int k = threadIdx.x & 63, c = threadIdx.x >> 6;
        float s = 0.f;
        const float* row = W2 + (size_t)k * DIMN + c * 256;
        #pragma unroll 8
        for (int j = 0; j < 256; ++j) s += row[j];
        partw[c][k] = s;
        __syncthreads();
        if (c == 0) w2sum[k] = partw[0][k] + partw[1][k] + partw[2][k] + partw[3][k];
    }
    int gid = blockIdx.x * blockDim.x + threadIdx.x;
    int nt = gridDim.x * blockDim.x;
    float dt = 1.0f / (1.0f + expf(-dtp[0]));
    for (int i = gid; i < 2048 * 64; i += nt) {
        unsigned short b = f2bf(W1[i]);
        W1bf[i] = b;
        int k = i >> 6, n = i & 63;
        W1Tbf[n * 2048 + k] = b;
    }
    for (int i = gid; i < 64 * 1024; i += nt) {
        int k = i >> 10, n = i & 1023;
        W2Tbf[n * 64 + k] = f2bf(W2[i]);
    }
    for (int i = gid; i < 64 * 1024; i += nt) {
        int n = i >> 10, k = i & 1023;
        W1qdT[i] = f2bf((dt / mass[k]) * W1[k * 64 + n]);
    }
    for (int i = gid; i < DIMN; i += nt) dtm[i] = dt / mass[i];
}

// ---------------- mnkern: MN = W1q^T (diag(dtm) W1q + W1p), Nm = W1q^T W1p ----------------
// 64x64 fp32 outputs via bf16 MFMA, K=1024. 16 waves. (unchanged, known-correct)

__global__ __launch_bounds__(256)
void mnkern(const unsigned short* __restrict__ W1T, const unsigned short* __restrict__ W1qdT,
            float* __restrict__ MN, float* __restrict__ Nm) {
    const int wv = threadIdx.x >> 6, lane = threadIdx.x & 63;
    const int l16 = lane & 15, quad = lane >> 4, kq = quad * 8;
    const int gw = blockIdx.x * 4 + wv;       // 0..15
    const int mt = gw >> 2, nt = gw & 3;
    f32x4 accMd = {0,0,0,0}, accN = {0,0,0,0};
    #pragma unroll 4
    for (int it = 0; it < 32; ++it) {
        int k = it * 32 + kq;
        bf16x8 af = *(const bf16x8*)(W1T + (size_t)(mt * 16 + l16) * 2048 + k);
        bf16x8 bd = *(const bf16x8*)(W1qdT + (size_t)(nt * 16 + l16) * 1024 + k);
        bf16x8 bp = *(const bf16x8*)(W1T + (size_t)(nt * 16 + l16) * 2048 + 1024 + k);
        accMd = __builtin_amdgcn_mfma_f32_16x16x32_bf16(af, bd, accMd, 0, 0, 0);
        accN  = __builtin_amdgcn_mfma_f32_16x16x32_bf16(af, bp, accN, 0, 0, 0);
    }
    #pragma unroll
    for (int rg = 0; rg < 4; ++rg) {
        int row = mt * 16 + quad * 4 + rg;
        int col = nt * 16 + l16;
        MN[row * 64 + col] = accMd[rg] + accN[rg];
        Nm[row * 64 + col] = accN[rg];
    }
}

// ---------------- zchain: z-GEMM (K-split, prefetched) + LDS reduce + per-row chain ----------------
// Block = 16 rows, 4 waves each doing a 256-col K-slice of q AND p with depth-1
// register prefetch (keeps >=4 float4 loads in flight while pack8+MFMA run).
// After the LDS reduce each thread holds z1,zdp for 4 rows (lane = column) and
// runs the fp32 leapfrog chain, emitting u1, u1+u2, gelu(z1)-gelu(z3) as bf16.

__global__ __launch_bounds__(256, 4)
void zchain(const float* __restrict__ q, const float* __restrict__ p,
            const unsigned short* __restrict__ W1T, const unsigned short* __restrict__ W1qdT,
            const float* __restrict__ b1,
            const float* __restrict__ MN, const float* __restrict__ Nm,
            const float* __restrict__ w2sum, const float* __restrict__ dtp,
            unsigned short* __restrict__ u1b, unsigned short* __restrict__ usb,
            unsigned short* __restrict__ g13) {
    __shared__ float part[4 * 64 * 34];       // 34.8 KB partials, stride 34 (2-way max)
    __shared__ float ubuf[4 * 256];           // 4 KB wave-private broadcast buffers
    const int wv = threadIdx.x >> 6, lane = threadIdx.x & 63;
    const int l16 = lane & 15, quad = lane >> 4, kq = quad * 8;
    const int tile = blockIdx.x;              // 16-row tile, 0..1023
    const size_t arow = (size_t)tile * 16 + l16;
    const float* rq = q + arow * DIMN + wv * 256;
    const float* rp = p + arow * DIMN + wv * 256;

    f32x4 accz[4] = {{0,0,0,0},{0,0,0,0},{0,0,0,0},{0,0,0,0}};
    f32x4 accd[4] = {{0,0,0,0},{0,0,0,0},{0,0,0,0},{0,0,0,0}};

    // ---- phase 1: z partials with explicit depth-1 prefetch ----
    float4 cq0 = *(const float4*)(rq + kq);
    float4 cq1 = *(const float4*)(rq + kq + 4);
    float4 cp0 = *(const float4*)(rp + kq);
    float4 cp1 = *(const float4*)(rp + kq + 4);
    #pragma unroll
    for (int it = 0; it < 8; ++it) {
        float4 nq0 = {0,0,0,0}, nq1 = {0,0,0,0}, np0 = {0,0,0,0}, np1 = {0,0,0,0};
        if (it < 7) {
            int kn = (it + 1) * 32 + kq;
            nq0 = *(const float4*)(rq + kn); nq1 = *(const float4*)(rq + kn + 4);
            np0 = *(const float4*)(rp + kn); np1 = *(const float4*)(rp + kn + 4);
        }
        const int k = wv * 256 + it * 32 + kq;
        bf16x8 aq = pack8(cq0, cq1);
        bf16x8 ap = pack8(cp0, cp1);
        #pragma unroll
        for (int c = 0; c < 4; ++c) {
            bf16x8 bq = *(const bf16x8*)(W1T + (size_t)(c * 16 + l16) * 2048 + k);
            accz[c] = __builtin_amdgcn_mfma_f32_16x16x32_bf16(aq, bq, accz[c], 0, 0, 0);
        }
        #pragma unroll
        for (int c = 0; c < 4; ++c) {
            bf16x8 bp = *(const bf16x8*)(W1T + (size_t)(c * 16 + l16) * 2048 + 1024 + k);
            accz[c] = __builtin_amdgcn_mfma_f32_16x16x32_bf16(ap, bp, accz[c], 0, 0, 0);
            bf16x8 bd = *(const bf16x8*)(W1qdT + (size_t)(c * 16 + l16) * 1024 + k);
            accd[c] = __builtin_amdgcn_mfma_f32_16x16x32_bf16(ap, bd, accd[c], 0, 0, 0);
        }
        cq0 = nq0; cq1 = nq1; cp0 = np0; cp1 = np1;
    }

    // ---- phase 2: write partials, block reduce ----
    float* myp = part + (size_t)(wv * 64 + lane) * 34;
    #pragma unroll
    for (int c = 0; c < 4; ++c) {
        #pragma unroll
        for (int rg = 0; rg < 4; ++rg) {
            myp[c * 4 + rg] = accz[c][rg];
            myp[16 + c * 4 + rg] = accd[c][rg];
        }
    }
    __syncthreads();

    // this thread owns rows {wv, wv+4, wv+8, wv+12} of the tile, col = lane
    float z1v[4], zdv[4];
    #pragma unroll
    for (int kk = 0; kk < 4; ++kk) {
        const int row = wv + kk * 4, col = lane;
        const int ln = ((row >> 2) << 4) | (col & 15);
        const int j = ((col >> 4) << 2) | (row & 3);
        float sz = b1[col], sd = 0.f;
        #pragma unroll
        for (int w = 0; w < 4; ++w) {
            const float* pp = part + (size_t)(w * 64 + ln) * 34;
            sz += pp[j];
            sd += pp[16 + j];
        }
        z1v[kk] = sz;
        zdv[kk] = sd;
    }

    // ---- phase 3: per-row fp32 chain (wave-private LDS broadcast) ----
    float* ub = ubuf + wv * 256;
    const float ws = w2sum[lane];
    const float hdt = 0.5f / (1.0f + expf(-dtp[0]));

    float u1[4], h1[4];
    #pragma unroll
    for (int r = 0; r < 4; ++r) {
        u1[r] = dgeluf(z1v[r]) * ws;
        h1[r] = geluf(z1v[r]);
        ub[r * 64 + lane] = u1[r];
    }
    float acc[4] = {0.f, 0.f, 0.f, 0.f};
    #pragma unroll 8
    for (int k = 0; k < 64; ++k) {
        float m = MN[k * 64 + lane];
        acc[0] += ub[k] * m;
        acc[1] += ub[64 + k] * m;
        acc[2] += ub[128 + k] * m;
        acc[3] += ub[192 + k] * m;
    }
    float z2[4], u2[4];
    #pragma unroll
    for (int r = 0; r < 4; ++r) {
        z2[r] = z1v[r] + zdv[r] - hdt * acc[r];
        u2[r] = dgeluf(z2[r]) * ws;
        ub[r * 64 + lane] = u2[r];
    }
    float acc2[4] = {0.f, 0.f, 0.f, 0.f};
    #pragma unroll 8
    for (int k = 0; k < 64; ++k) {
        float m = Nm[k * 64 + lane];
        acc2[0] += ub[k] * m;
        acc2[1] += ub[64 + k] * m;
        acc2[2] += ub[128 + k] * m;
        acc2[3] += ub[192 + k] * m;
    }
    #pragma unroll
    for (int r = 0; r < 4; ++r) {
        float z3 = z2[r] - hdt * acc2[r];
        size_t o = ((size_t)tile * 16 + wv + r * 4) * 64 + lane;
        u1b[o] = f2bf(u1[r]);
        usb[o] = f2bf(u1[r] + u2[r]);
        g13[o] = f2bf(h1[r] - geluf(z3));
    }
}

// ---------------- wide4: all three 64-MB outputs, 4 col-tiles per wave ----------------
// Wave owns 16 rows x 64 cols: A-frags (u1/us/g13) loaded ONCE, then 4 col-tiles of
// {Dq = u1@W1q^T, Ds = (u1+u2)@W1q^T, E = g13@W2} with fused epilogue.

__global__ __launch_bounds__(256, 4)
void wide4(const unsigned short* __restrict__ u1b, const unsigned short* __restrict__ usb,
           const unsigned short* __restrict__ g13,
           const unsigned short* __restrict__ W1bf, const unsigned short* __restrict__ W2T,
           const float* __restrict__ q, const float* __restrict__ p,
           const float* __restrict__ dtm, const float* __restrict__ dtp,
           float* __restrict__ outq, float* __restrict__ outp, float* __restrict__ oute) {
    const int wv = threadIdx.x >> 6, lane = threadIdx.x & 63;
    const int l16 = lane & 15, quad = lane >> 4, kq = quad * 8;
    const int gw = blockIdx.x * 4 + wv;       // 0..16383
    const int mt = gw >> 4;                   // row-tile 0..1023
    const int ng = (gw & 15) * 4;             // first of 4 col-tiles
    const size_t arow = (size_t)mt * 16 + l16;

    bf16x8 au0 = *(const bf16x8*)(u1b + arow * 64 + kq);
    bf16x8 au1 = *(const bf16x8*)(u1b + arow * 64 + 32 + kq);
    bf16x8 as0 = *(const bf16x8*)(usb + arow * 64 + kq);
    bf16x8 as1 = *(const bf16x8*)(usb + arow * 64 + 32 + kq);
    bf16x8 ag0 = *(const bf16x8*)(g13 + arow * 64 + kq);
    bf16x8 ag1 = *(const bf16x8*)(g13 + arow * 64 + 32 + kq);

    const float hdt = 0.5f / (1.0f + expf(-dtp[0]));

    #pragma unroll
    for (int t = 0; t < 4; ++t) {
        const int n0 = (ng + t) * 16;
        bf16x8 bw0 = *(const bf16x8*)(W1bf + (size_t)(n0 + l16) * 64 + kq);
        bf16x8 bw1 = *(const bf16x8*)(W1bf + (size_t)(n0 + l16) * 64 + 32 + kq);
        bf16x8 b20 = *(const bf16x8*)(W2T + (size_t)(n0 + l16) * 64 + kq);
        bf16x8 b21 = *(const bf16x8*)(W2T + (size_t)(n0 + l16) * 64 + 32 + kq);

        f32x4 accq = {0,0,0,0}, accs = {0,0,0,0}, acce = {0,0,0,0};
        accq = __builtin_amdgcn_mfma_f32_16x16x32_bf16(au0, bw0, accq, 0, 0, 0);
        accq = __builtin_amdgcn_mfma_f32_16x16x32_bf16(au1, bw1, accq, 0, 0, 0);
        accs = __builtin_amdgcn_mfma_f32_16x16x32_bf16(as0, bw0, accs, 0, 0, 0);
        accs = __builtin_amdgcn_mfma_f32_16x16x32_bf16(as1, bw1, accs, 0, 0, 0);
        acce = __builtin_amdgcn_mfma_f32_16x16x32_bf16(ag0, b20, acce, 0, 0, 0);
        acce = __builtin_amdgcn_mfma_f32_16x16x32_bf16(ag1, b21, acce, 0, 0, 0);

        const int i = n0 + l16;
        const float dm = dtm[i];
        #pragma unroll
        for (int rg = 0; rg < 4; ++rg) {
            size_t idx = (size_t)(mt * 16 + quad * 4 + rg) * DIMN + i;
            float qv = q[idx], pv = p[idx];
            float ph = pv - hdt * accq[rg];
            outq[idx] = qv + dm * ph;
            outp[idx] = pv - hdt * accs[rg];
            oute[idx] = fabsf(acce[rg]);
        }
    }
}

// ---------------- launch ----------------

extern "C" void kernel_launch(void* const* d_in, const int* in_sizes, int n_in,
                              void* d_out, int out_size, void* d_ws, size_t ws_size,
                              hipStream_t stream) {
    const float* q    = (const float*)d_in[0];
    const float* p    = (const float*)d_in[1];
    const float* W1   = (const float*)d_in[2];
    const float* b1   = (const float*)d_in[3];
    const float* W2   = (const float*)d_in[4];
    /* b2 = d_in[5] cancels everywhere */
    const float* mass = (const float*)d_in[6];
    const float* dtp  = (const float*)d_in[7];

    float* out  = (float*)d_out;
    float* outq = out;
    float* outp = out + (size_t)BROWS * DIMN;
    float* oute = out + (size_t)2 * BROWS * DIMN;

    char* ws = (char*)d_ws;
    unsigned short* W1bf  = (unsigned short*)(ws);              // 256 KB [2048][64]
    unsigned short* W1Tbf = (unsigned short*)(ws + 262144);     // 256 KB [64][2048]
    unsigned short* W2Tbf = (unsigned short*)(ws + 524288);     // 128 KB [1024][64]
    float* w2sum          = (float*)(ws + 655360);              // 256 B
    float* dtm            = (float*)(ws + 655616);              // 4 KB
    unsigned short* W1qdT = (unsigned short*)(ws + 659712);     // 128 KB [64][1024]
    float* MN             = (float*)(ws + 790784);              // 16 KB [64][64]
    float* Nm             = (float*)(ws + 807168);              // 16 KB [64][64]
    unsigned short* u1b   = (unsigned short*)(ws + 9437184);    // 2 MB
    unsigned short* usb   = (unsigned short*)(ws + 11534336);   // 2 MB
    unsigned short* g13   = (unsigned short*)(ws + 13631488);   // 2 MB

    hipLaunchKernelGGL(prep_kernel, dim3(256), dim3(256), 0, stream,
                       W1, W2, mass, dtp, W1bf, W1Tbf, W2Tbf, W1qdT, dtm, w2sum);
    hipLaunchKernelGGL(mnkern, dim3(4), dim3(256), 0, stream, W1Tbf, W1qdT, MN, Nm);
    hipLaunchKernelGGL(zchain, dim3(1024), dim3(256), 0, stream,
                       q, p, W1Tbf, W1qdT, b1, MN, Nm, w2sum, dtp, u1b, usb, g13);
    hipLaunchKernelGGL(wide4, dim3(4096), dim3(256), 0, stream,
                       u1b, usb, g13, W1bf, W2Tbf, q, p, dtm, dtp, outq, outp, oute);
}

// Round 4
// 417.083 us; speedup vs baseline: 1.5021x; 1.0274x over previous
//
#include <hip/hip_runtime.h>
#include <stdint.h>

#define BROWS 16384
#define DIMN 1024
#define HIDN 64

typedef __attribute__((ext_vector_type(8))) short bf16x8;
typedef __attribute__((ext_vector_type(4))) float f32x4;

__device__ __forceinline__ unsigned short f2bf(float f) {
    union { float f; unsigned int u; } v; v.f = f;
    unsigned int u = v.u;
    u += 0x7fffu + ((u >> 16) & 1u);   // round-to-nearest-even
    return (unsigned short)(u >> 16);
}

__device__ __forceinline__ bf16x8 pack8(float4 a, float4 b) {
    bf16x8 r;
    r[0] = (short)f2bf(a.x); r[1] = (short)f2bf(a.y);
    r[2] = (short)f2bf(a.z); r[3] = (short)f2bf(a.w);
    r[4] = (short)f2bf(b.x); r[5] = (short)f2bf(b.y);
    r[6] = (short)f2bf(b.z); r[7] = (short)f2bf(b.w);
    return r;
}

__device__ __forceinline__ float geluf(float x) {
    return 0.5f * x * (1.0f + erff(x * 0.70710678118654752f));
}
__device__ __forceinline__ float dgeluf(float x) {
    float c = 0.5f * (1.0f + erff(x * 0.70710678118654752f));
    return c + x * 0.3989422804014327f * expf(-0.5f * x * x);
}

// ---------------- prep: w2sum (block 0) + bf16 weight packs ----------------
// W1bf  [2048][64]  : W1 rows, bf16 (B^T for D = u @ W1q^T)
// W1Tbf [64][2048]  : W1^T, bf16 (B^T for z = X @ W1, A for mnkern)
// W2Tbf [1024][64]  : W2^T, bf16 (B^T for E = g @ W2)
// W1qdT [64][1024]  : (diag(dt/mass) @ W1q)^T, bf16

__global__ void prep_kernel(const float* __restrict__ W1, const float* __restrict__ W2,
                            const float* __restrict__ mass, const float* __restrict__ dtp,
                            unsigned short* __restrict__ W1bf,
                            unsigned short* __restrict__ W1Tbf,
                            unsigned short* __restrict__ W2Tbf,
                            unsigned short* __restrict__ W1qdT,
                            float* __restrict__ dtm, float* __restrict__ w2sum) {
    if (blockIdx.x == 0) {   // w2sum[k] = sum_j W2[k][j]
        __shared__ float partw[4][64];
        int k = threadIdx.x & 63, c = threadIdx.x >> 6;
        float s = 0.f;
        const float* row = W2 + (size_t)k * DIMN + c * 256;
        #pragma unroll 8
        for (int j = 0; j < 256; ++j) s += row[j];
        partw[c][k] = s;
        __syncthreads();
        if (c == 0) w2sum[k] = partw[0][k] + partw[1][k] + partw[2][k] + partw[3][k];
    }
    int gid = blockIdx.x * blockDim.x + threadIdx.x;
    int nt = gridDim.x * blockDim.x;
    float dt = 1.0f / (1.0f + expf(-dtp[0]));
    for (int i = gid; i < 2048 * 64; i += nt) {
        unsigned short b = f2bf(W1[i]);
        W1bf[i] = b;
        int k = i >> 6, n = i & 63;
        W1Tbf[n * 2048 + k] = b;
    }
    for (int i = gid; i < 64 * 1024; i += nt) {
        int k = i >> 10, n = i & 1023;
        W2Tbf[n * 64 + k] = f2bf(W2[i]);
    }
    for (int i = gid; i < 64 * 1024; i += nt) {
        int n = i >> 10, k = i & 1023;
        W1qdT[i] = f2bf((dt / mass[k]) * W1[k * 64 + n]);
    }
    for (int i = gid; i < DIMN; i += nt) dtm[i] = dt / mass[i];
}

// ---------------- mnkern: MN = W1q^T (diag(dtm) W1q + W1p), Nm = W1q^T W1p ----------------
// 64x64 fp32 outputs via bf16 MFMA, K=1024. 16 waves. (known-correct)

__global__ __launch_bounds__(256)
void mnkern(const unsigned short* __restrict__ W1T, const unsigned short* __restrict__ W1qdT,
            float* __restrict__ MN, float* __restrict__ Nm) {
    const int wv = threadIdx.x >> 6, lane = threadIdx.x & 63;
    const int l16 = lane & 15, quad = lane >> 4, kq = quad * 8;
    const int gw = blockIdx.x * 4 + wv;       // 0..15
    const int mt = gw >> 2, nt = gw & 3;
    f32x4 accMd = {0,0,0,0}, accN = {0,0,0,0};
    #pragma unroll 4
    for (int it = 0; it < 32; ++it) {
        int k = it * 32 + kq;
        bf16x8 af = *(const bf16x8*)(W1T + (size_t)(mt * 16 + l16) * 2048 + k);
        bf16x8 bd = *(const bf16x8*)(W1qdT + (size_t)(nt * 16 + l16) * 1024 + k);
        bf16x8 bp = *(const bf16x8*)(W1T + (size_t)(nt * 16 + l16) * 2048 + 1024 + k);
        accMd = __builtin_amdgcn_mfma_f32_16x16x32_bf16(af, bd, accMd, 0, 0, 0);
        accN  = __builtin_amdgcn_mfma_f32_16x16x32_bf16(af, bp, accN, 0, 0, 0);
    }
    #pragma unroll
    for (int rg = 0; rg < 4; ++rg) {
        int row = mt * 16 + quad * 4 + rg;
        int col = nt * 16 + l16;
        MN[row * 64 + col] = accMd[rg] + accN[rg];
        Nm[row * 64 + col] = accN[rg];
    }
}

// ---------------- megakern: whole leapfrog for a 16-row tile in one block ----------------
// Phase 1: z-GEMM partials (4 waves x 256-col K-slices of q AND p, depth-1 prefetch)
// Phase 2: LDS reduce -> z1,zdp in registers (thread owns 4 rows, col = lane)
// Phase 3: fp32 chain -> u1, u1+u2, gelu(z1)-gelu(z3) as bf16 INTO LDS
// Phase 4: wide GEMM: each wave does 16 col-tiles (4 waves x 16 = all 64) + epilogue.
// q/p re-reads in phase 4 hit L2/L3 (read by this block in phase 1).

__global__ __launch_bounds__(256, 4)
void megakern(const float* __restrict__ q, const float* __restrict__ p,
              const unsigned short* __restrict__ W1T, const unsigned short* __restrict__ W1qdT,
              const unsigned short* __restrict__ W1bf, const unsigned short* __restrict__ W2T,
              const float* __restrict__ b1,
              const float* __restrict__ MN, const float* __restrict__ Nm,
              const float* __restrict__ w2sum, const float* __restrict__ dtm,
              const float* __restrict__ dtp,
              float* __restrict__ outq, float* __restrict__ outp, float* __restrict__ oute) {
    __shared__ float part[4 * 64 * 34];       // 34.8 KB; phase-3 buffers aliased inside
    const int wv = threadIdx.x >> 6, lane = threadIdx.x & 63;
    const int l16 = lane & 15, quad = lane >> 4, kq = quad * 8;
    const int tile = blockIdx.x;              // 16-row tile, 0..1023
    const size_t arow = (size_t)tile * 16 + l16;
    const float* rq = q + arow * DIMN + wv * 256;
    const float* rp = p + arow * DIMN + wv * 256;

    f32x4 accz[4] = {{0,0,0,0},{0,0,0,0},{0,0,0,0},{0,0,0,0}};
    f32x4 accd[4] = {{0,0,0,0},{0,0,0,0},{0,0,0,0},{0,0,0,0}};

    // ---- phase 1: z partials with depth-1 register prefetch ----
    float4 cq0 = *(const float4*)(rq + kq);
    float4 cq1 = *(const float4*)(rq + kq + 4);
    float4 cp0 = *(const float4*)(rp + kq);
    float4 cp1 = *(const float4*)(rp + kq + 4);
    #pragma unroll
    for (int it = 0; it < 8; ++it) {
        float4 nq0 = {0,0,0,0}, nq1 = {0,0,0,0}, np0 = {0,0,0,0}, np1 = {0,0,0,0};
        if (it < 7) {
            int kn = (it + 1) * 32 + kq;
            nq0 = *(const float4*)(rq + kn); nq1 = *(const float4*)(rq + kn + 4);
            np0 = *(const float4*)(rp + kn); np1 = *(const float4*)(rp + kn + 4);
        }
        const int k = wv * 256 + it * 32 + kq;
        bf16x8 aq = pack8(cq0, cq1);
        bf16x8 ap = pack8(cp0, cp1);
        #pragma unroll
        for (int c = 0; c < 4; ++c) {
            bf16x8 bq = *(const bf16x8*)(W1T + (size_t)(c * 16 + l16) * 2048 + k);
            accz[c] = __builtin_amdgcn_mfma_f32_16x16x32_bf16(aq, bq, accz[c], 0, 0, 0);
        }
        #pragma unroll
        for (int c = 0; c < 4; ++c) {
            bf16x8 bp = *(const bf16x8*)(W1T + (size_t)(c * 16 + l16) * 2048 + 1024 + k);
            accz[c] = __builtin_amdgcn_mfma_f32_16x16x32_bf16(ap, bp, accz[c], 0, 0, 0);
            bf16x8 bd = *(const bf16x8*)(W1qdT + (size_t)(c * 16 + l16) * 1024 + k);
            accd[c] = __builtin_amdgcn_mfma_f32_16x16x32_bf16(ap, bd, accd[c], 0, 0, 0);
        }
        cq0 = nq0; cq1 = nq1; cp0 = np0; cp1 = np1;
    }

    // ---- phase 2: write partials, block reduce ----
    float* myp = part + (size_t)(wv * 64 + lane) * 34;
    #pragma unroll
    for (int c = 0; c < 4; ++c) {
        #pragma unroll
        for (int rg = 0; rg < 4; ++rg) {
            myp[c * 4 + rg] = accz[c][rg];
            myp[16 + c * 4 + rg] = accd[c][rg];
        }
    }
    __syncthreads();

    // thread owns rows {wv, wv+4, wv+8, wv+12}, col = lane
    float z1v[4], zdv[4];
    #pragma unroll
    for (int kk = 0; kk < 4; ++kk) {
        const int ln = (kk << 4) | l16;        // lane that held (row=wv+4kk, col=lane)
        const int j = (quad << 2) | wv;        // reg index within that lane
        float sz = b1[lane], sd = 0.f;
        #pragma unroll
        for (int w = 0; w < 4; ++w) {
            const float* pp = part + (size_t)(w * 64 + ln) * 34;
            sz += pp[j];
            sd += pp[16 + j];
        }
        z1v[kk] = sz;
        zdv[kk] = sd;
    }
    __syncthreads();   // everyone done reading part; safe to alias below

    // aliased buffers inside part:
    //   ubuf  : floats [0 .. 1024)            (4 KB, wave-private 256 each)
    //   ubf16 : shorts at float offset 1024   (3 x [16][72] bf16 = 6.75 KB)
    float* ub = part + wv * 256;
    unsigned short* ubf16 = (unsigned short*)(part + 1024);
    unsigned short* u1lds = ubf16;
    unsigned short* uslds = ubf16 + 16 * 72;
    unsigned short* g13lds = ubf16 + 2 * 16 * 72;

    // ---- phase 3: per-row fp32 chain ----
    const float ws = w2sum[lane];
    const float hdt = 0.5f / (1.0f + expf(-dtp[0]));

    float u1[4], h1[4];
    #pragma unroll
    for (int r = 0; r < 4; ++r) {
        u1[r] = dgeluf(z1v[r]) * ws;
        h1[r] = geluf(z1v[r]);
        ub[r * 64 + lane] = u1[r];
    }
    float acc[4] = {0.f, 0.f, 0.f, 0.f};
    #pragma unroll 8
    for (int k = 0; k < 64; ++k) {
        float m = MN[k * 64 + lane];
        acc[0] += ub[k] * m;
        acc[1] += ub[64 + k] * m;
        acc[2] += ub[128 + k] * m;
        acc[3] += ub[192 + k] * m;
    }
    float z2[4], u2[4];
    #pragma unroll
    for (int r = 0; r < 4; ++r) {
        z2[r] = z1v[r] + zdv[r] - hdt * acc[r];
        u2[r] = dgeluf(z2[r]) * ws;
        ub[r * 64 + lane] = u2[r];
    }
    float acc2[4] = {0.f, 0.f, 0.f, 0.f};
    #pragma unroll 8
    for (int k = 0; k < 64; ++k) {
        float m = Nm[k * 64 + lane];
        acc2[0] += ub[k] * m;
        acc2[1] += ub[64 + k] * m;
        acc2[2] += ub[128 + k] * m;
        acc2[3] += ub[192 + k] * m;
    }
    #pragma unroll
    for (int r = 0; r < 4; ++r) {
        float z3 = z2[r] - hdt * acc2[r];
        const int row = wv + r * 4;
        u1lds[row * 72 + lane] = f2bf(u1[r]);
        uslds[row * 72 + lane] = f2bf(u1[r] + u2[r]);
        g13lds[row * 72 + lane] = f2bf(h1[r] - geluf(z3));
    }
    __syncthreads();

    // ---- phase 4: wide GEMM, 16 col-tiles per wave (4 waves cover all 64), fused epilogue ----
    const bf16x8 au0 = *(const bf16x8*)(u1lds + l16 * 72 + kq);
    const bf16x8 au1 = *(const bf16x8*)(u1lds + l16 * 72 + 32 + kq);
    const bf16x8 as0 = *(const bf16x8*)(uslds + l16 * 72 + kq);
    const bf16x8 as1 = *(const bf16x8*)(uslds + l16 * 72 + 32 + kq);
    const bf16x8 ag0 = *(const bf16x8*)(g13lds + l16 * 72 + kq);
    const bf16x8 ag1 = *(const bf16x8*)(g13lds + l16 * 72 + 32 + kq);

    #pragma unroll 2
    for (int t = 0; t < 16; ++t) {
        const int n0 = (wv * 16 + t) * 16;     // col-tiles 0..63 across the 4 waves
        bf16x8 bw0 = *(const bf16x8*)(W1bf + (size_t)(n0 + l16) * 64 + kq);
        bf16x8 bw1 = *(const bf16x8*)(W1bf + (size_t)(n0 + l16) * 64 + 32 + kq);
        bf16x8 b20 = *(const bf16x8*)(W2T + (size_t)(n0 + l16) * 64 + kq);
        bf16x8 b21 = *(const bf16x8*)(W2T + (size_t)(n0 + l16) * 64 + 32 + kq);

        f32x4 accq = {0,0,0,0}, accs = {0,0,0,0}, acce = {0,0,0,0};
        accq = __builtin_amdgcn_mfma_f32_16x16x32_bf16(au0, bw0, accq, 0, 0, 0);
        accq = __builtin_amdgcn_mfma_f32_16x16x32_bf16(au1, bw1, accq, 0, 0, 0);
        accs = __builtin_amdgcn_mfma_f32_16x16x32_bf16(as0, bw0, accs, 0, 0, 0);
        accs = __builtin_amdgcn_mfma_f32_16x16x32_bf16(as1, bw1, accs, 0, 0, 0);
        acce = __builtin_amdgcn_mfma_f32_16x16x32_bf16(ag0, b20, acce, 0, 0, 0);
        acce = __builtin_amdgcn_mfma_f32_16x16x32_bf16(ag1, b21, acce, 0, 0, 0);

        const int i = n0 + l16;
        const float dm = dtm[i];
        #pragma unroll
        for (int rg = 0; rg < 4; ++rg) {
            size_t idx = (size_t)(tile * 16 + quad * 4 + rg) * DIMN + i;
            float qv = q[idx], pv = p[idx];
            float ph = pv - hdt * accq[rg];
            __builtin_nontemporal_store(qv + dm * ph, &outq[idx]);
            __builtin_nontemporal_store(pv - hdt * accs[rg], &outp[idx]);
            __builtin_nontemporal_store(fabsf(acce[rg]), &oute[idx]);
        }
    }
}

// ---------------- launch ----------------

extern "C" void kernel_launch(void* const* d_in, const int* in_sizes, int n_in,
                              void* d_out, int out_size, void* d_ws, size_t ws_size,
                              hipStream_t stream) {
    const float* q    = (const float*)d_in[0];
    const float* p    = (const float*)d_in[1];
    const float* W1   = (const float*)d_in[2];
    const float* b1   = (const float*)d_in[3];
    const float* W2   = (const float*)d_in[4];
    /* b2 = d_in[5] cancels everywhere */
    const float* mass = (const float*)d_in[6];
    const float* dtp  = (const float*)d_in[7];

    float* out  = (float*)d_out;
    float* outq = out;
    float* outp = out + (size_t)BROWS * DIMN;
    float* oute = out + (size_t)2 * BROWS * DIMN;

    char* ws = (char*)d_ws;
    unsigned short* W1bf  = (unsigned short*)(ws);              // 256 KB [2048][64]
    unsigned short* W1Tbf = (unsigned short*)(ws + 262144);     // 256 KB [64][2048]
    unsigned short* W2Tbf = (unsigned short*)(ws + 524288);     // 128 KB [1024][64]
    float* w2sum          = (float*)(ws + 655360);              // 256 B
    float* dtm            = (float*)(ws + 655616);              // 4 KB
    unsigned short* W1qdT = (unsigned short*)(ws + 659712);     // 128 KB [64][1024]
    float* MN             = (float*)(ws + 790784);              // 16 KB [64][64]
    float* Nm             = (float*)(ws + 807168);              // 16 KB [64][64]

    hipLaunchKernelGGL(prep_kernel, dim3(256), dim3(256), 0, stream,
                       W1, W2, mass, dtp, W1bf, W1Tbf, W2Tbf, W1qdT, dtm, w2sum);
    hipLaunchKernelGGL(mnkern, dim3(4), dim3(256), 0, stream, W1Tbf, W1qdT, MN, Nm);
    hipLaunchKernelGGL(megakern, dim3(1024), dim3(256), 0, stream,
                       q, p, W1Tbf, W1qdT, W1bf, W2Tbf, b1, MN, Nm,
                       w2sum, dtm, dtp, outq, outp, oute);
}